// Round 1
// baseline (149.400 us; speedup 1.0000x reference)
//
#include <hip/hip_runtime.h>

// ---------------------------------------------------------------------------
// VisionEncoder (PASSING since R12, absmax 1.95e-3): project -> SAT -> fused
// pool/LN/GEMM2. V4 coordinate semantics (XLA reciprocal-multiply) verified.
//
// R15: K1 moved to MFMA via bf16 hi/lo split (Dekker): fp32 a = hi + lo,
//   D = Ahi*Bhi + Alo*Bhi + Ahi*Blo (lo*lo ~2^-17 rel, dropped). Keeps
//   fp32-level accuracy (absmax must stay ~2e-3) while using the 2.5 PF
//   matrix pipe instead of the 157 TF vector pipe.
//   K0 split_w1   : W1 -> W1T_hi/lo bf16, transposed [n][k] so B-frags are
//                   contiguous 16B loads (frag k=(lane>>4)*8+j, col=lane&15)
//   K1 gemm_u_mfma: 64 rows x 128 cols/block, wave w owns rows w*16..+15
//                   (A read exactly once from HBM), no LDS, no barriers.
//                   SPLITK 8 -> 4 (MFMA blocks are cheap; halves U traffic)
//   K2 prefix_x   : sums 4 partials, x-scan -> SAT
//   K3 prefix_y   : y-scan in LDS
//   K4 pool_proj  : parallel LN stats, GEMM2 (unchanged)
// ---------------------------------------------------------------------------

#define HD 128
#define SPLITK 4

typedef __attribute__((ext_vector_type(8))) short bf16x8;
typedef __attribute__((ext_vector_type(4))) float f32x4;

__device__ __forceinline__ int decode_dim(const int* p, int fallback) {
    if (p == nullptr) return fallback;
    int vi = *p;
    if (vi >= 1 && vi <= 1000000) return vi;
    float vf = __int_as_float(vi);
    if (vf >= 1.0f && vf <= 1000000.0f) return (int)vf;
    return fallback;
}

// V4 (verified R12): trunc( fl32( fl32(x * fl32(1/W)) * n ) ), bit-exact via
// f64; optnone so no fast-math rewrite can touch it.
__attribute__((noinline, optnone))
__device__ int coord_map(int x, int W, int n) {
    double rd = 1.0 / (double)W;
    float r = (float)rd;
    double qd = (double)x * (double)r;
    float q = (float)qd;
    double pd = (double)q * (double)n;
    float p = (float)pd;
    return (int)p;
}

// ---------------------------------------------------------------------------
// K0: W1[E][HD] fp32 -> W1T_hi/W1T_lo[HD][E] bf16 (truncation split, exact
// Dekker remainder: hi = trunc16(x), lo = trunc16(x - hi), |err| ~ 2^-17|x|).
// ---------------------------------------------------------------------------
__global__ __launch_bounds__(256) void split_w1_kernel(
    const float* __restrict__ W1, unsigned short* __restrict__ Whi,
    unsigned short* __restrict__ Wlo, int E)
{
    __shared__ float tile[64][65];
    int t = threadIdx.x;
    int k0 = blockIdx.x * 64, n0 = blockIdx.y * 64;

    int r = t >> 4, c4 = (t & 15) * 4;
#pragma unroll
    for (int i = 0; i < 4; ++i) {
        int kr = r + i * 16;
        *(float4*)&tile[kr][c4] =
            *(const float4*)&W1[(size_t)(k0 + kr) * HD + n0 + c4];
    }
    __syncthreads();

    int nl = t >> 2, kq = (t & 3) * 16;
    unsigned hp[8], lp[8];
#pragma unroll
    for (int j = 0; j < 8; ++j) {
        float x0 = tile[kq + 2 * j][nl];
        float x1 = tile[kq + 2 * j + 1][nl];
        unsigned u0 = __float_as_uint(x0);
        unsigned u1 = __float_as_uint(x1);
        float l0 = x0 - __uint_as_float(u0 & 0xffff0000u);
        float l1 = x1 - __uint_as_float(u1 & 0xffff0000u);
        hp[j] = (u0 >> 16) | (u1 & 0xffff0000u);
        lp[j] = (__float_as_uint(l0) >> 16) | (__float_as_uint(l1) & 0xffff0000u);
    }
    size_t off = (size_t)(n0 + nl) * E + k0 + kq;
    *(uint4*)(Whi + off)     = make_uint4(hp[0], hp[1], hp[2], hp[3]);
    *(uint4*)(Whi + off + 8) = make_uint4(hp[4], hp[5], hp[6], hp[7]);
    *(uint4*)(Wlo + off)     = make_uint4(lp[0], lp[1], lp[2], lp[3]);
    *(uint4*)(Wlo + off + 8) = make_uint4(lp[4], lp[5], lp[6], lp[7]);
}

// ---------------------------------------------------------------------------
// K1: MFMA partial GEMM. Block = 64 rows x 128 cols, 4 waves; wave w owns
// rows [w*16, w*16+16) x all 128 cols = 8 tiles of 16x16, K-chunk = E/4.
// A frag: T direct from global (row = lane&15, k = (lane>>4)*8+j), split to
// bf16 hi/lo in-register. B frag: 16B loads from pre-split W1T (L2-resident).
// C/D layout (verified m89/m91): col = lane&15, row = (lane>>4)*4 + reg.
// ---------------------------------------------------------------------------
__global__ __launch_bounds__(256) void gemm_u_mfma(
    const float* __restrict__ T, const unsigned short* __restrict__ Whi,
    const unsigned short* __restrict__ Wlo, float* __restrict__ U,
    int P, int E)
{
    int t = threadIdx.x;
    int lane = t & 63;
    int w = t >> 6;
    int row0 = blockIdx.x * 64 + w * 16;
    int kchunk = E >> 2;                       // E / SPLITK
    int kbase = blockIdx.y * kchunk;
    float* Uo = U + (size_t)blockIdx.y * (size_t)P * HD;

    int lr  = lane & 15;
    int lkq = (lane >> 4) * 8;

    int arow = row0 + lr; if (arow >= P) arow = P - 1;
    const float* ap = T + (size_t)arow * E + kbase + lkq;
    const unsigned short* bh0 = Whi + (size_t)lr * E + kbase + lkq;
    const unsigned short* bl0 = Wlo + (size_t)lr * E + kbase + lkq;

    f32x4 acc[8];
#pragma unroll
    for (int n = 0; n < 8; ++n) acc[n] = (f32x4){0.f, 0.f, 0.f, 0.f};

    for (int kt = 0; kt < kchunk; kt += 32) {
        float4 a0 = *(const float4*)(ap + kt);
        float4 a1 = *(const float4*)(ap + kt + 4);
        float av[8] = {a0.x, a0.y, a0.z, a0.w, a1.x, a1.y, a1.z, a1.w};
        bf16x8 ahi, alo;
#pragma unroll
        for (int j = 0; j < 8; ++j) {
            unsigned u = __float_as_uint(av[j]);
            ahi[j] = (short)(u >> 16);
            float l = av[j] - __uint_as_float(u & 0xffff0000u);
            alo[j] = (short)(__float_as_uint(l) >> 16);
        }
#pragma unroll
        for (int n = 0; n < 8; ++n) {
            bf16x8 bhi = *(const bf16x8*)(bh0 + (size_t)(n * 16) * E + kt);
            bf16x8 blo = *(const bf16x8*)(bl0 + (size_t)(n * 16) * E + kt);
            acc[n] = __builtin_amdgcn_mfma_f32_16x16x32_bf16(ahi, bhi, acc[n], 0, 0, 0);
            acc[n] = __builtin_amdgcn_mfma_f32_16x16x32_bf16(alo, bhi, acc[n], 0, 0, 0);
            acc[n] = __builtin_amdgcn_mfma_f32_16x16x32_bf16(ahi, blo, acc[n], 0, 0, 0);
        }
    }

    int cr0 = row0 + (lane >> 4) * 4;
    int cc  = lane & 15;
#pragma unroll
    for (int n = 0; n < 8; ++n) {
#pragma unroll
        for (int r = 0; r < 4; ++r) {
            int p = cr0 + r;
            if (p < P) Uo[(size_t)p * HD + n * 16 + cc] = acc[n][r];
        }
    }
}

// ---------------------------------------------------------------------------
// K2: block (y, chalf): sum SPLITK partials of row y (74 x 64ch), x-scan,
// write SAT row y+1 (+ col-0 border).
// ---------------------------------------------------------------------------
__global__ __launch_bounds__(256) void prefix_x_kernel(
    const float* __restrict__ U, float* __restrict__ S,
    int P, int npw, int nph)
{
    extern __shared__ float tile[];            // npw*64 floats
    int t = threadIdx.x;
    int y = blockIdx.x;
    int ch0 = blockIdx.y * 64;
    size_t ustride = (size_t)P * HD;
    size_t ubase = (size_t)y * npw * HD + ch0;

    int nj = npw * 16;                         // float4 groups
    for (int j = t; j < nj; j += 256) {
        int x = j >> 4, cq = (j & 15) * 4;
        size_t off = ubase + (size_t)x * HD + cq;
        float4 s = *(const float4*)(U + off);
#pragma unroll
        for (int p = 1; p < SPLITK; ++p) {
            float4 v = *(const float4*)(U + (size_t)p * ustride + off);
            s.x += v.x; s.y += v.y; s.z += v.z; s.w += v.w;
        }
        *(float4*)&tile[x * 64 + cq] = s;
    }
    __syncthreads();

    if (t < 64) {
        int c = t;
        size_t srow = (size_t)(y + 1) * (npw + 1) * HD + ch0;
        S[srow + c] = 0.f;                     // col-0 border
        float acc = 0.f;
        for (int x = 0; x < npw; ++x) {
            acc += tile[x * 64 + c];
            S[srow + (size_t)(x + 1) * HD + c] = acc;
        }
    }
}

// ---------------------------------------------------------------------------
// K3: block (x, chalf): stage column x (y=1..nph) through LDS, y-scan,
// write back (+ row-0 border).
// ---------------------------------------------------------------------------
__global__ __launch_bounds__(256) void prefix_y_kernel(
    float* __restrict__ S, int npw, int nph)
{
    extern __shared__ float tile[];            // nph*64 floats
    int t = threadIdx.x;
    int x = blockIdx.x;
    int ch0 = blockIdx.y * 64;
    size_t stride = (size_t)(npw + 1) * HD;
    size_t base = (size_t)x * HD + ch0;

    int nj = nph * 16;
    for (int j = t; j < nj; j += 256) {
        int y = j >> 4, cq = (j & 15) * 4;
        *(float4*)&tile[y * 64 + cq] =
            *(const float4*)(S + base + (size_t)(y + 1) * stride + cq);
    }
    __syncthreads();

    if (t < 64) {
        int c = t;
        S[base + c] = 0.f;                     // row-0 border
        float acc = 0.f;
        for (int y = 0; y < nph; ++y) {
            acc += tile[y * 64 + c];
            S[base + (size_t)(y + 1) * stride + c] = acc;
        }
    }
}

// ---------------------------------------------------------------------------
// K4: 16 boxes x 128 cols; parallel LN stats; fp32 out.
// ---------------------------------------------------------------------------
__global__ __launch_bounds__(256) void pool_proj_kernel(
    const float* __restrict__ S, const int* __restrict__ bboxes,
    const int* __restrict__ pH, const int* __restrict__ pW,
    const float* __restrict__ b1, const float* __restrict__ gamma,
    const float* __restrict__ beta, const float* __restrict__ W2,
    const float* __restrict__ b2, float* __restrict__ out,
    int Nb, int npw, int nph, int fbW, int fbH)
{
    __shared__ float hs[16][HD + 1];
    __shared__ float Bs[32][HD];
    __shared__ float red_s[16][17], red_q[16][17];
    __shared__ int   cI11[16], cI12[16], cI21[16], cI22[16];
    __shared__ float cCnt[16];
    __shared__ float mu_s[16], rs_s[16];

    int t = threadIdx.x;
    int c = t & 127;
    int rh = t >> 7;
    int row0 = blockIdx.x * 16;

    if (t < 16) {
        int b = row0 + t; if (b >= Nb) b = Nb - 1;
        int x1 = bboxes[b * 4 + 0];
        int y1 = bboxes[b * 4 + 1];
        int x2 = bboxes[b * 4 + 2];
        int y2 = bboxes[b * 4 + 3];
        int Wi = decode_dim(pW, fbW);
        int Hi = decode_dim(pH, fbH);
        int px1 = coord_map(x1, Wi, npw);
        int px2 = coord_map(x2, Wi, npw);
        int py1 = coord_map(y1, Hi, nph);
        int py2 = coord_map(y2, Hi, nph);
        px1 = min(max(px1, 0), npw - 1);
        px2 = max(px1 + 1, min(px2, npw));
        py1 = min(max(py1, 0), nph - 1);
        py2 = max(py1 + 1, min(py2, nph));
        int st = npw + 1;
        cI11[t] = (py1 * st + px1) * HD;
        cI12[t] = (py1 * st + px2) * HD;
        cI21[t] = (py2 * st + px1) * HD;
        cI22[t] = (py2 * st + px2) * HD;
        cCnt[t] = (float)((py2 - py1) * (px2 - px1));
    }
    __syncthreads();

    float bias1 = b1[c];
    float hv[8];
#pragma unroll
    for (int r = 0; r < 8; ++r) {
        int row = rh * 8 + r;
        float s = S[cI22[row] + c] - S[cI12[row] + c]
                - S[cI21[row] + c] + S[cI11[row] + c];
        hv[r] = s / cCnt[row] + bias1;
        hs[row][c] = hv[r];
    }
    __syncthreads();

    // parallel LN stats: 16 threads per row, 8 elements each
    {
        int sr = t & 15;           // row
        int sg = t >> 4;           // group 0..15
        float ps = 0.f, pq = 0.f;
#pragma unroll
        for (int i = 0; i < 8; ++i) {
            float v = hs[sr][sg * 8 + i];
            ps += v; pq += v * v;
        }
        red_s[sr][sg] = ps; red_q[sr][sg] = pq;
    }
    __syncthreads();
    if (t < 16) {
        float s = 0.f, q = 0.f;
#pragma unroll
        for (int i = 0; i < 16; ++i) { s += red_s[t][i]; q += red_q[t][i]; }
        float m = s * (1.0f / HD);
        float v = q * (1.0f / HD) - m * m;
        mu_s[t] = m;
        rs_s[t] = rsqrtf(v + 1e-5f);
    }
    __syncthreads();

    float g = gamma[c], be = beta[c];
#pragma unroll
    for (int r = 0; r < 8; ++r) {
        int row = rh * 8 + r;
        float x = (hv[r] - mu_s[row]) * rs_s[row] * g + be;
        hs[row][c] = fmaxf(x, 0.f);
    }
    __syncthreads();

    float bias2 = b2[c];
    float acc2[8];
#pragma unroll
    for (int r = 0; r < 8; ++r) acc2[r] = bias2;
    for (int k0 = 0; k0 < HD; k0 += 32) {
#pragma unroll
        for (int i = 0; i < 16; ++i) {
            int idx = t + i * 256;
            int kk = idx >> 7, cc = idx & 127;
            Bs[kk][cc] = W2[(size_t)(k0 + kk) * HD + cc];
        }
        __syncthreads();
#pragma unroll
        for (int kk = 0; kk < 32; ++kk) {
            float bv = Bs[kk][c];
#pragma unroll
            for (int r = 0; r < 8; ++r)
                acc2[r] += hs[rh * 8 + r][k0 + kk] * bv;
        }
        __syncthreads();
    }

#pragma unroll
    for (int r = 0; r < 8; ++r) {
        int rg = row0 + rh * 8 + r;
        if (rg < Nb) out[(size_t)rg * HD + c] = acc2[r];
    }
}

extern "C" void kernel_launch(void* const* d_in, const int* in_sizes, int n_in,
                              void* d_out, int out_size, void* d_ws, size_t ws_size,
                              hipStream_t stream) {
    int iT = 0, iB = 1, iH = 2, iW = 3, iW1 = 4, ib1 = 5, ig = 6, ibe = 7,
        iW2 = 8, ib2 = 9;
    bool has_scalars = (n_in >= 10 && in_sizes[2] == 1 && in_sizes[3] == 1);
    if (!has_scalars) { iW1 = 2; ib1 = 3; ig = 4; ibe = 5; iW2 = 6; ib2 = 7; }

    const float* tokens = (const float*)d_in[iT];
    const int*   bboxes = (const int*)d_in[iB];
    const int*   pH     = has_scalars ? (const int*)d_in[iH] : nullptr;
    const int*   pW     = has_scalars ? (const int*)d_in[iW] : nullptr;
    const float* W1     = (const float*)d_in[iW1];
    const float* b1     = (const float*)d_in[ib1];
    const float* gamma  = (const float*)d_in[ig];
    const float* beta   = (const float*)d_in[ibe];
    const float* W2     = (const float*)d_in[iW2];
    const float* b2     = (const float*)d_in[ib2];
    float* out = (float*)d_out;

    int Hd = in_sizes[ib1];               // 128
    int E  = in_sizes[iW1] / Hd;          // 1024
    int Nb = in_sizes[iB] / 4;            // 4096
    int P  = in_sizes[iT] / E;            // 5476
    int npw = 1;
    while ((npw + 1) * (npw + 1) <= P) ++npw;  // 74
    int nph = P / npw;
    (void)out_size; (void)ws_size;

    // Workspace: S (2.88 MB) + 4 partial U buffers (11.2 MB)
    //          + W1T_hi/lo bf16 (256 KB each) = ~14.6 MB (ws 256 MB).
    float* S = (float*)d_ws;
    size_t s_elems = ((size_t)(nph + 1) * (npw + 1) * HD + 255) & ~(size_t)255;
    float* U = S + s_elems;
    size_t u_elems = (size_t)SPLITK * (size_t)P * HD;
    unsigned short* Whi = (unsigned short*)(U + u_elems);
    unsigned short* Wlo = Whi + (size_t)E * HD;

    split_w1_kernel<<<dim3(E / 64, HD / 64), dim3(256), 0, stream>>>(
        W1, Whi, Wlo, E);

    int mtiles = (P + 63) / 64;
    gemm_u_mfma<<<dim3(mtiles, SPLITK), dim3(256), 0, stream>>>(
        tokens, Whi, Wlo, U, P, E);
    prefix_x_kernel<<<dim3(nph, 2), dim3(256), (size_t)npw * 64 * 4, stream>>>(
        U, S, P, npw, nph);
    prefix_y_kernel<<<dim3(npw + 1, 2), dim3(256), (size_t)nph * 64 * 4, stream>>>(
        S, npw, nph);
    pool_proj_kernel<<<dim3((Nb + 15) / 16), dim3(256), 0, stream>>>(
        S, bboxes, pH, pW, b1, gamma, beta, W2, b2, out, Nb, npw, nph,
        14 * npw, 14 * nph);
}

// Round 2
// 145.373 us; speedup vs baseline: 1.0277x; 1.0277x over previous
//
#include <hip/hip_runtime.h>

// ---------------------------------------------------------------------------
// VisionEncoder (PASSING since R12): project -> SAT -> fused pool/LN/GEMM2.
// V4 coordinate semantics (XLA reciprocal-multiply) verified.
//
// R16: K1 MFMA latency fix. R15's MFMA port was latency-bound (44.5us,
//   Occ 10%, MfmaUtil 3%): 344 blocks = 1.34/CU, no prefetch, dependent
//   HBM->split->L2->MFMA chain exposed. Changes:
//   - tile 32 rows x 128 cols, wave = 16 rows x 64 cols (acc[4], ~90 VGPR)
//   - SPLITK 8 -> grid 172x8 = 1376 blocks (5.4/CU)
//   - software pipeline: prefetch next A; batch all 8 B loads before the
//     split+MFMA cluster (L2 latency overlaps VALU split)
//   - RNE bf16 splits (K0 + in-register A): absmax drifted 3.9e-3 w/ trunc
//   K2 prefix_x   : sums 8 partials, x-scan -> SAT
//   K3 prefix_y   : y-scan in LDS
//   K4 pool_proj  : parallel LN stats, GEMM2 (unchanged)
// ---------------------------------------------------------------------------

#define HD 128
#define SPLITK 8

typedef __attribute__((ext_vector_type(8))) short bf16x8;
typedef __attribute__((ext_vector_type(4))) float f32x4;

__device__ __forceinline__ int decode_dim(const int* p, int fallback) {
    if (p == nullptr) return fallback;
    int vi = *p;
    if (vi >= 1 && vi <= 1000000) return vi;
    float vf = __int_as_float(vi);
    if (vf >= 1.0f && vf <= 1000000.0f) return (int)vf;
    return fallback;
}

// V4 (verified R12): trunc( fl32( fl32(x * fl32(1/W)) * n ) ), bit-exact via
// f64; optnone so no fast-math rewrite can touch it.
__attribute__((noinline, optnone))
__device__ int coord_map(int x, int W, int n) {
    double rd = 1.0 / (double)W;
    float r = (float)rd;
    double qd = (double)x * (double)r;
    float q = (float)qd;
    double pd = (double)q * (double)n;
    float p = (float)pd;
    return (int)p;
}

// round-to-nearest-even fp32 -> bf16 (as raw u16)
__device__ __forceinline__ unsigned short bf16_rne(float x) {
    unsigned u = __float_as_uint(x);
    unsigned r = u + 0x7fffu + ((u >> 16) & 1u);
    return (unsigned short)(r >> 16);
}

// ---------------------------------------------------------------------------
// K0: W1[E][HD] fp32 -> W1T_hi/W1T_lo[HD][E] bf16. Veltkamp/Dekker RNE split:
// hi = rne16(x) (exact residual), lo = rne16(x - hi), |err| ~ 2^-18 |x|.
// ---------------------------------------------------------------------------
__global__ __launch_bounds__(256) void split_w1_kernel(
    const float* __restrict__ W1, unsigned short* __restrict__ Whi,
    unsigned short* __restrict__ Wlo, int E)
{
    __shared__ float tile[64][65];
    int t = threadIdx.x;
    int k0 = blockIdx.x * 64, n0 = blockIdx.y * 64;

    int r = t >> 4, c4 = (t & 15) * 4;
#pragma unroll
    for (int i = 0; i < 4; ++i) {
        int kr = r + i * 16;
        *(float4*)&tile[kr][c4] =
            *(const float4*)&W1[(size_t)(k0 + kr) * HD + n0 + c4];
    }
    __syncthreads();

    int nl = t >> 2, kq = (t & 3) * 16;
    unsigned hp[8], lp[8];
#pragma unroll
    for (int j = 0; j < 8; ++j) {
        float x0 = tile[kq + 2 * j][nl];
        float x1 = tile[kq + 2 * j + 1][nl];
        unsigned h0 = bf16_rne(x0);
        unsigned h1 = bf16_rne(x1);
        float l0 = x0 - __uint_as_float(h0 << 16);
        float l1 = x1 - __uint_as_float(h1 << 16);
        hp[j] = h0 | ((unsigned)h1 << 16);
        lp[j] = (unsigned)bf16_rne(l0) | ((unsigned)bf16_rne(l1) << 16);
    }
    size_t off = (size_t)(n0 + nl) * E + k0 + kq;
    *(uint4*)(Whi + off)     = make_uint4(hp[0], hp[1], hp[2], hp[3]);
    *(uint4*)(Whi + off + 8) = make_uint4(hp[4], hp[5], hp[6], hp[7]);
    *(uint4*)(Wlo + off)     = make_uint4(lp[0], lp[1], lp[2], lp[3]);
    *(uint4*)(Wlo + off + 8) = make_uint4(lp[4], lp[5], lp[6], lp[7]);
}

// ---------------------------------------------------------------------------
// K1: MFMA partial GEMM. Block = 32 rows x 128 cols, 4 waves:
//   wave w: rows (w&1)*16, cols (w>>1)*64 (4 n-tiles of 16).
// A frag: T direct from global (row = lane&15, k = (lane>>4)*8+j), RNE split
// to bf16 hi/lo in-register; next-iteration A prefetched in registers.
// B frag: all 8 16B loads issued before the split (L2-resident, latency
// overlapped with VALU). D = Ahi*Bhi + Alo*Bhi + Ahi*Blo.
// C/D layout (verified m89/m91): col = lane&15, row = (lane>>4)*4 + reg.
// ---------------------------------------------------------------------------
__global__ __launch_bounds__(256) void gemm_u_mfma(
    const float* __restrict__ T, const unsigned short* __restrict__ Whi,
    const unsigned short* __restrict__ Wlo, float* __restrict__ U,
    int P, int E)
{
    int t = threadIdx.x;
    int lane = t & 63;
    int w = t >> 6;
    int row0 = blockIdx.x * 32 + (w & 1) * 16;
    int col0 = (w >> 1) * 64;
    int kchunk = E >> 3;                       // E / SPLITK = 128
    int kbase = blockIdx.y * kchunk;
    float* Uo = U + (size_t)blockIdx.y * (size_t)P * HD;

    int lr  = lane & 15;
    int lkq = (lane >> 4) * 8;

    int arow = row0 + lr; if (arow >= P) arow = P - 1;
    const float* ap = T + (size_t)arow * E + kbase + lkq;
    const unsigned short* bh0 = Whi + (size_t)(col0 + lr) * E + kbase + lkq;
    const unsigned short* bl0 = Wlo + (size_t)(col0 + lr) * E + kbase + lkq;

    f32x4 acc[4];
#pragma unroll
    for (int n = 0; n < 4; ++n) acc[n] = (f32x4){0.f, 0.f, 0.f, 0.f};

    float4 ca0 = *(const float4*)(ap);
    float4 ca1 = *(const float4*)(ap + 4);

    for (int kt = 0; kt < kchunk; kt += 32) {
        // prefetch next A while this iteration computes
        float4 na0 = ca0, na1 = ca1;
        if (kt + 32 < kchunk) {
            na0 = *(const float4*)(ap + kt + 32);
            na1 = *(const float4*)(ap + kt + 36);
        }
        // issue all B loads up front (latency hides under the split below)
        bf16x8 bhv[4], blv[4];
#pragma unroll
        for (int n = 0; n < 4; ++n) {
            bhv[n] = *(const bf16x8*)(bh0 + (size_t)(n * 16) * E + kt);
            blv[n] = *(const bf16x8*)(bl0 + (size_t)(n * 16) * E + kt);
        }

        float av[8] = {ca0.x, ca0.y, ca0.z, ca0.w, ca1.x, ca1.y, ca1.z, ca1.w};
        bf16x8 ahi, alo;
#pragma unroll
        for (int j = 0; j < 8; ++j) {
            unsigned h = bf16_rne(av[j]);
            ahi[j] = (short)h;
            float l = av[j] - __uint_as_float(h << 16);
            alo[j] = (short)bf16_rne(l);
        }

#pragma unroll
        for (int n = 0; n < 4; ++n) {
            acc[n] = __builtin_amdgcn_mfma_f32_16x16x32_bf16(ahi, bhv[n], acc[n], 0, 0, 0);
            acc[n] = __builtin_amdgcn_mfma_f32_16x16x32_bf16(alo, bhv[n], acc[n], 0, 0, 0);
            acc[n] = __builtin_amdgcn_mfma_f32_16x16x32_bf16(ahi, blv[n], acc[n], 0, 0, 0);
        }
        ca0 = na0; ca1 = na1;
    }

    int cr0 = row0 + (lane >> 4) * 4;
    int cc  = lane & 15;
#pragma unroll
    for (int n = 0; n < 4; ++n) {
#pragma unroll
        for (int r = 0; r < 4; ++r) {
            int p = cr0 + r;
            if (p < P) Uo[(size_t)p * HD + col0 + n * 16 + cc] = acc[n][r];
        }
    }
}

// ---------------------------------------------------------------------------
// K2: block (y, chalf): sum SPLITK partials of row y (74 x 64ch), x-scan,
// write SAT row y+1 (+ col-0 border).
// ---------------------------------------------------------------------------
__global__ __launch_bounds__(256) void prefix_x_kernel(
    const float* __restrict__ U, float* __restrict__ S,
    int P, int npw, int nph)
{
    extern __shared__ float tile[];            // npw*64 floats
    int t = threadIdx.x;
    int y = blockIdx.x;
    int ch0 = blockIdx.y * 64;
    size_t ustride = (size_t)P * HD;
    size_t ubase = (size_t)y * npw * HD + ch0;

    int nj = npw * 16;                         // float4 groups
    for (int j = t; j < nj; j += 256) {
        int x = j >> 4, cq = (j & 15) * 4;
        size_t off = ubase + (size_t)x * HD + cq;
        float4 s = *(const float4*)(U + off);
#pragma unroll
        for (int p = 1; p < SPLITK; ++p) {
            float4 v = *(const float4*)(U + (size_t)p * ustride + off);
            s.x += v.x; s.y += v.y; s.z += v.z; s.w += v.w;
        }
        *(float4*)&tile[x * 64 + cq] = s;
    }
    __syncthreads();

    if (t < 64) {
        int c = t;
        size_t srow = (size_t)(y + 1) * (npw + 1) * HD + ch0;
        S[srow + c] = 0.f;                     // col-0 border
        float acc = 0.f;
        for (int x = 0; x < npw; ++x) {
            acc += tile[x * 64 + c];
            S[srow + (size_t)(x + 1) * HD + c] = acc;
        }
    }
}

// ---------------------------------------------------------------------------
// K3: block (x, chalf): stage column x (y=1..nph) through LDS, y-scan,
// write back (+ row-0 border).
// ---------------------------------------------------------------------------
__global__ __launch_bounds__(256) void prefix_y_kernel(
    float* __restrict__ S, int npw, int nph)
{
    extern __shared__ float tile[];            // nph*64 floats
    int t = threadIdx.x;
    int x = blockIdx.x;
    int ch0 = blockIdx.y * 64;
    size_t stride = (size_t)(npw + 1) * HD;
    size_t base = (size_t)x * HD + ch0;

    int nj = nph * 16;
    for (int j = t; j < nj; j += 256) {
        int y = j >> 4, cq = (j & 15) * 4;
        *(float4*)&tile[y * 64 + cq] =
            *(const float4*)(S + base + (size_t)(y + 1) * stride + cq);
    }
    __syncthreads();

    if (t < 64) {
        int c = t;
        S[base + c] = 0.f;                     // row-0 border
        float acc = 0.f;
        for (int y = 0; y < nph; ++y) {
            acc += tile[y * 64 + c];
            S[base + (size_t)(y + 1) * stride + c] = acc;
        }
    }
}

// ---------------------------------------------------------------------------
// K4: 16 boxes x 128 cols; parallel LN stats; fp32 out.
// ---------------------------------------------------------------------------
__global__ __launch_bounds__(256) void pool_proj_kernel(
    const float* __restrict__ S, const int* __restrict__ bboxes,
    const int* __restrict__ pH, const int* __restrict__ pW,
    const float* __restrict__ b1, const float* __restrict__ gamma,
    const float* __restrict__ beta, const float* __restrict__ W2,
    const float* __restrict__ b2, float* __restrict__ out,
    int Nb, int npw, int nph, int fbW, int fbH)
{
    __shared__ float hs[16][HD + 1];
    __shared__ float Bs[32][HD];
    __shared__ float red_s[16][17], red_q[16][17];
    __shared__ int   cI11[16], cI12[16], cI21[16], cI22[16];
    __shared__ float cCnt[16];
    __shared__ float mu_s[16], rs_s[16];

    int t = threadIdx.x;
    int c = t & 127;
    int rh = t >> 7;
    int row0 = blockIdx.x * 16;

    if (t < 16) {
        int b = row0 + t; if (b >= Nb) b = Nb - 1;
        int x1 = bboxes[b * 4 + 0];
        int y1 = bboxes[b * 4 + 1];
        int x2 = bboxes[b * 4 + 2];
        int y2 = bboxes[b * 4 + 3];
        int Wi = decode_dim(pW, fbW);
        int Hi = decode_dim(pH, fbH);
        int px1 = coord_map(x1, Wi, npw);
        int px2 = coord_map(x2, Wi, npw);
        int py1 = coord_map(y1, Hi, nph);
        int py2 = coord_map(y2, Hi, nph);
        px1 = min(max(px1, 0), npw - 1);
        px2 = max(px1 + 1, min(px2, npw));
        py1 = min(max(py1, 0), nph - 1);
        py2 = max(py1 + 1, min(py2, nph));
        int st = npw + 1;
        cI11[t] = (py1 * st + px1) * HD;
        cI12[t] = (py1 * st + px2) * HD;
        cI21[t] = (py2 * st + px1) * HD;
        cI22[t] = (py2 * st + px2) * HD;
        cCnt[t] = (float)((py2 - py1) * (px2 - px1));
    }
    __syncthreads();

    float bias1 = b1[c];
    float hv[8];
#pragma unroll
    for (int r = 0; r < 8; ++r) {
        int row = rh * 8 + r;
        float s = S[cI22[row] + c] - S[cI12[row] + c]
                - S[cI21[row] + c] + S[cI11[row] + c];
        hv[r] = s / cCnt[row] + bias1;
        hs[row][c] = hv[r];
    }
    __syncthreads();

    // parallel LN stats: 16 threads per row, 8 elements each
    {
        int sr = t & 15;           // row
        int sg = t >> 4;           // group 0..15
        float ps = 0.f, pq = 0.f;
#pragma unroll
        for (int i = 0; i < 8; ++i) {
            float v = hs[sr][sg * 8 + i];
            ps += v; pq += v * v;
        }
        red_s[sr][sg] = ps; red_q[sr][sg] = pq;
    }
    __syncthreads();
    if (t < 16) {
        float s = 0.f, q = 0.f;
#pragma unroll
        for (int i = 0; i < 16; ++i) { s += red_s[t][i]; q += red_q[t][i]; }
        float m = s * (1.0f / HD);
        float v = q * (1.0f / HD) - m * m;
        mu_s[t] = m;
        rs_s[t] = rsqrtf(v + 1e-5f);
    }
    __syncthreads();

    float g = gamma[c], be = beta[c];
#pragma unroll
    for (int r = 0; r < 8; ++r) {
        int row = rh * 8 + r;
        float x = (hv[r] - mu_s[row]) * rs_s[row] * g + be;
        hs[row][c] = fmaxf(x, 0.f);
    }
    __syncthreads();

    float bias2 = b2[c];
    float acc2[8];
#pragma unroll
    for (int r = 0; r < 8; ++r) acc2[r] = bias2;
    for (int k0 = 0; k0 < HD; k0 += 32) {
#pragma unroll
        for (int i = 0; i < 16; ++i) {
            int idx = t + i * 256;
            int kk = idx >> 7, cc = idx & 127;
            Bs[kk][cc] = W2[(size_t)(k0 + kk) * HD + cc];
        }
        __syncthreads();
#pragma unroll
        for (int kk = 0; kk < 32; ++kk) {
            float bv = Bs[kk][c];
#pragma unroll
            for (int r = 0; r < 8; ++r)
                acc2[r] += hs[rh * 8 + r][k0 + kk] * bv;
        }
        __syncthreads();
    }

#pragma unroll
    for (int r = 0; r < 8; ++r) {
        int rg = row0 + rh * 8 + r;
        if (rg < Nb) out[(size_t)rg * HD + c] = acc2[r];
    }
}

extern "C" void kernel_launch(void* const* d_in, const int* in_sizes, int n_in,
                              void* d_out, int out_size, void* d_ws, size_t ws_size,
                              hipStream_t stream) {
    int iT = 0, iB = 1, iH = 2, iW = 3, iW1 = 4, ib1 = 5, ig = 6, ibe = 7,
        iW2 = 8, ib2 = 9;
    bool has_scalars = (n_in >= 10 && in_sizes[2] == 1 && in_sizes[3] == 1);
    if (!has_scalars) { iW1 = 2; ib1 = 3; ig = 4; ibe = 5; iW2 = 6; ib2 = 7; }

    const float* tokens = (const float*)d_in[iT];
    const int*   bboxes = (const int*)d_in[iB];
    const int*   pH     = has_scalars ? (const int*)d_in[iH] : nullptr;
    const int*   pW     = has_scalars ? (const int*)d_in[iW] : nullptr;
    const float* W1     = (const float*)d_in[iW1];
    const float* b1     = (const float*)d_in[ib1];
    const float* gamma  = (const float*)d_in[ig];
    const float* beta   = (const float*)d_in[ibe];
    const float* W2     = (const float*)d_in[iW2];
    const float* b2     = (const float*)d_in[ib2];
    float* out = (float*)d_out;

    int Hd = in_sizes[ib1];               // 128
    int E  = in_sizes[iW1] / Hd;          // 1024
    int Nb = in_sizes[iB] / 4;            // 4096
    int P  = in_sizes[iT] / E;            // 5476
    int npw = 1;
    while ((npw + 1) * (npw + 1) <= P) ++npw;  // 74
    int nph = P / npw;
    (void)out_size; (void)ws_size;

    // Workspace: S (2.88 MB) + 8 partial U buffers (22.4 MB)
    //          + W1T_hi/lo bf16 (256 KB each) = ~25.8 MB (ws 256 MB).
    float* S = (float*)d_ws;
    size_t s_elems = ((size_t)(nph + 1) * (npw + 1) * HD + 255) & ~(size_t)255;
    float* U = S + s_elems;
    size_t u_elems = (size_t)SPLITK * (size_t)P * HD;
    unsigned short* Whi = (unsigned short*)(U + u_elems);
    unsigned short* Wlo = Whi + (size_t)E * HD;

    split_w1_kernel<<<dim3(E / 64, HD / 64), dim3(256), 0, stream>>>(
        W1, Whi, Wlo, E);

    int mtiles = (P + 31) / 32;
    gemm_u_mfma<<<dim3(mtiles, SPLITK), dim3(256), 0, stream>>>(
        tokens, Whi, Wlo, U, P, E);
    prefix_x_kernel<<<dim3(nph, 2), dim3(256), (size_t)npw * 64 * 4, stream>>>(
        U, S, P, npw, nph);
    prefix_y_kernel<<<dim3(npw + 1, 2), dim3(256), (size_t)nph * 64 * 4, stream>>>(
        S, npw, nph);
    pool_proj_kernel<<<dim3((Nb + 15) / 16), dim3(256), 0, stream>>>(
        S, bboxes, pH, pW, b1, gamma, beta, W2, b2, out, Nb, npw, nph,
        14 * npw, 14 * nph);
}